// Round 17
// baseline (332.464 us; speedup 1.0000x reference)
//
#include <hip/hip_runtime.h>
#include <hip/hip_bf16.h>
#include <math.h>

typedef unsigned int u32;
typedef unsigned long long u64;
typedef unsigned short u16;
typedef __bf16 bf16x8 __attribute__((ext_vector_type(8)));
typedef float f32x4 __attribute__((ext_vector_type(4)));

#define DEV __device__ __forceinline__

DEV u32 bfr(float f){ u32 u = __float_as_uint(f); return (u + 0x7fffu + ((u>>16)&1u)) >> 16; }
DEV u16 b1v(float a){ return __builtin_bit_cast(u16, (__bf16)a); }
DEV u32 pk2(float a, float b){
  return (u32)__builtin_bit_cast(u16, (__bf16)a) | ((u32)__builtin_bit_cast(u16, (__bf16)b) << 16);
}
DEV float red32(float v){
  v += __shfl_xor(v,1); v += __shfl_xor(v,2); v += __shfl_xor(v,4);
  v += __shfl_xor(v,8); v += __shfl_xor(v,16); return v;
}

// ---------------- init: slots = mu + exp(ls)*noise ----------------
__global__ void kInitSlots(const float* __restrict__ noise, const float* __restrict__ mu,
                           const float* __restrict__ ls, float* __restrict__ slots){
  int i4 = blockIdx.x*256 + threadIdx.x;
  int d4 = i4 & 31;
  float4 nv = ((const float4*)noise)[i4];
  float4 mv = ((const float4*)mu)[d4];
  float4 lv = ((const float4*)ls)[d4];
  float4 r;
  r.x = mv.x + expf(lv.x)*nv.x;
  r.y = mv.y + expf(lv.y)*nv.y;
  r.z = mv.z + expf(lv.z)*nv.z;
  r.w = mv.w + expf(lv.w)*nv.w;
  ((float4*)slots)[i4] = r;
}

// ---------------- init: Wg = [Wk;Wv]*g (bf16) with k-PERMUTED columns ----------------
__global__ void kInitW(const float* __restrict__ Wk, const float* __restrict__ Wv,
                       const float* __restrict__ g, const float* __restrict__ bb,
                       u16* __restrict__ wg, float* __restrict__ c1, float* __restrict__ c2){
  int e = threadIdx.x;
  const float4* src = (const float4*)((e < 128) ? (Wk + e*128) : (Wv + (e-128)*128));
  const float4* g4 = (const float4*)g;
  const float4* b4 = (const float4*)bb;
  float a1 = 0.f, a2 = 0.f;
  #pragma unroll
  for (int gr = 0; gr < 16; ++gr){
    int kt = gr >> 2, h = gr & 3;
    int iA = kt*8 + h, iB = kt*8 + 4 + h;
    float4 wa = src[iA], wb = src[iB];
    float4 ga = g4[iA], gb = g4[iB];
    float4 ba = b4[iA], bbv = b4[iB];
    a1 += wa.x*ga.x + wa.y*ga.y + wa.z*ga.z + wa.w*ga.w
        + wb.x*gb.x + wb.y*gb.y + wb.z*gb.z + wb.w*gb.w;
    a2 += wa.x*ba.x + wa.y*ba.y + wa.z*ba.z + wa.w*ba.w
        + wb.x*bbv.x + wb.y*bbv.y + wb.z*bbv.z + wb.w*bbv.w;
    uint4 o;
    o.x = pk2(wa.x*ga.x, wa.y*ga.y);
    o.y = pk2(wa.z*ga.z, wa.w*ga.w);
    o.z = pk2(wb.x*gb.x, wb.y*gb.y);
    o.w = pk2(wb.z*gb.z, wb.w*gb.w);
    *(uint4*)&wg[e*128 + gr*8] = o;
  }
  c1[e] = a1; c2[e] = a2;
}

// ---------------- init: transposed weight packs for kC ----------------
__global__ void kInitT(const float* __restrict__ Wih, const float* __restrict__ Whh,
                       const float* __restrict__ W1, const float* __restrict__ W2,
                       float2* __restrict__ gruT, float* __restrict__ w1T, float* __restrict__ w2T){
  int i = blockIdx.x*256 + threadIdx.x;
  if (i < 49152){
    int d = i / 384, g = i - d*384;
    gruT[i] = make_float2(Wih[g*128 + d], Whh[g*128 + d]);
  } else if (i < 81920){
    int j = i - 49152;
    int d = j >> 8, h = j & 255;
    w1T[j] = W1[h*128 + d];
  } else if (i < 114688){
    int q = i - 81920;
    int j = q >> 7, d = q & 127;
    w2T[q] = W2[d*256 + j];
  }
}

// ---------------- kernel A: fused-LN K/V projection via bf16 MFMA ----------------
// COLUMN-SPLIT variant: each block computes 64 output cols x 256 rows.
// acc[4] = 16 AGPR (was 32); target total regs <= 128 -> 128-reg HW quantum ->
// 4 waves/SIMD (2x round-14's pool). If compiler lands 113-128 V the quantum
// stays 256 -> neutral vs round-14 (bounded downside). (256,2): cap 128, no spill.
// x read 4x total (K/V x 2 col-halves) but L3-resident.
__global__ __launch_bounds__(256, 2) void kA(const float* __restrict__ x,
    const u16* __restrict__ wg, const float* __restrict__ c1g, const float* __restrict__ c2g,
    u16* __restrict__ kbuf, u16* __restrict__ vbuf)
{
  __shared__ __align__(16) u16 sWg[64*128];      // 16 KB: this block's 64 wg rows
  __shared__ __align__(16) u16 sE[4*16*64];      // 8 KB (4 waves x 2 KB)
  __shared__ float sC1[64], sC2[64];
  const int t = threadIdx.x, l = t & 63, w = t >> 6;   // w 0..3
  const int bid = blockIdx.x;
  const int half = (bid >> 3) & 1;                     // 0 = K cols, 1 = V cols
  const int colh = (bid >> 4) & 1;                     // 64-col half within half
  const int group = (bid & 7)*128 + (bid >> 5);        // 0..1023
  const int rowbase = group*256;
  const int cbase = half*128 + colh*64;                // wg row base

  const uint4* wg4 = (const uint4*)wg;
  #pragma unroll
  for (int p = 0; p < 4; ++p){
    int G = t + p*256;            // 0..1023 (64 rows x 16 granules)
    int row = G >> 4, g = G & 15;
    uint4 v = wg4[(cbase + row)*16 + g];
    *(uint4*)&sWg[row*128 + ((g ^ (row & 7)) << 3)] = v;
  }
  if (t < 64){ sC1[t] = c1g[cbase + t]; sC2[t] = c2g[cbase + t]; }
  __syncthreads();   // the ONLY barrier

  u16* dstbuf = half ? vbuf : kbuf;
  const float4* x4 = (const float4*)x;

  #pragma unroll 1
  for (int it = 0; it < 4; ++it){
    const int r0 = rowbase + it*64 + w*16;
    const int myrow = r0 + (l & 15);
    const int h = l >> 4;
    float s1 = 0.f, s2 = 0.f;
    uint4 af[4];
    #pragma unroll
    for (int kt = 0; kt < 4; ++kt){
      float4 A = x4[(size_t)myrow*32 + kt*8 + h];        // 64B-contig per 4-lane grp
      float4 B = x4[(size_t)myrow*32 + kt*8 + 4 + h];
      s1 += A.x + A.y + A.z + A.w + B.x + B.y + B.z + B.w;
      s2 += A.x*A.x + A.y*A.y + A.z*A.z + A.w*A.w
          + B.x*B.x + B.y*B.y + B.z*B.z + B.w*B.w;
      af[kt].x = pk2(A.x, A.y);
      af[kt].y = pk2(A.z, A.w);
      af[kt].z = pk2(B.x, B.y);
      af[kt].w = pk2(B.z, B.w);
    }
    s1 += __shfl_xor(s1, 16); s2 += __shfl_xor(s2, 16);
    s1 += __shfl_xor(s1, 32); s2 += __shfl_xor(s2, 32);
    float m = s1 * 0.0078125f;
    float rstd = rsqrtf(s2 * 0.0078125f - m*m + 1e-5f);
    f32x4 acc[4];
    #pragma unroll
    for (int c_ = 0; c_ < 4; ++c_) acc[c_] = (f32x4){0.f,0.f,0.f,0.f};
    #pragma unroll
    for (int ct = 0; ct < 4; ++ct){
      uint4 bf[4];
      #pragma unroll
      for (int kt = 0; kt < 4; ++kt){
        int wr = ct*16 + (l & 15);
        int g = kt*4 + h;
        bf[kt] = *(const uint4*)&sWg[wr*128 + ((g ^ (wr & 7)) << 3)];
      }
      #pragma unroll
      for (int kt = 0; kt < 4; ++kt)
        acc[ct] = __builtin_amdgcn_mfma_f32_16x16x32_bf16(
            __builtin_bit_cast(bf16x8, af[kt]),
            __builtin_bit_cast(bf16x8, bf[kt]),
            acc[ct], 0, 0, 0);
    }
    float mvp[4], rvp[4];
    #pragma unroll
    for (int r = 0; r < 4; ++r){
      int rl = h*4 + r;
      mvp[r] = __shfl(m, rl);
      rvp[r] = __shfl(rstd, rl);
    }
    #pragma unroll
    for (int ct = 0; ct < 4; ++ct){
      int col = ct*16 + (l & 15);              // 0..63 local
      float c1v = sC1[col], c2v = sC2[col];
      #pragma unroll
      for (int r = 0; r < 4; ++r){
        int rl = h*4 + r;
        float valf = rvp[r]*(acc[ct][r] - mvp[r]*c1v) + c2v;
        int gran = (col >> 3) ^ (rl & 7);
        sE[w*1024 + rl*64 + (gran << 3) + (col & 7)] = b1v(valf);
      }
    }
    uint4* dst4 = (uint4*)dstbuf;
    #pragma unroll
    for (int p = 0; p < 2; ++p){
      int fl = l + p*64;                       // 0..127 (16 rows x 8 granules)
      int nl = fl >> 3, gb = fl & 7;
      uint4 v = *(const uint4*)&sE[w*1024 + nl*64 + ((gb ^ (nl & 7)) << 3)];
      dst4[(size_t)(r0 + nl)*16 + colh*8 + gb] = v;
    }
  }
}

// ---------------- kernel Q: iteration-0 q from initial slots ----------------
__global__ __launch_bounds__(256) void kQ(const float* __restrict__ slots,
    const float* __restrict__ Wq, const float* __restrict__ lng, const float* __restrict__ lnb,
    uint4* __restrict__ qg)
{
  const int b = blockIdx.x, t = threadIdx.x;
  const int k8 = t >> 5, q32 = t & 31;
  __shared__ __align__(16) float sSn[1024];
  __shared__ __align__(16) float sQ[1024];
  {
    float4 sv = ((const float4*)slots)[b*256 + t];
    float s  = sv.x + sv.y + sv.z + sv.w;
    float ss = sv.x*sv.x + sv.y*sv.y + sv.z*sv.z + sv.w*sv.w;
    s = red32(s); ss = red32(ss);
    float m = s*0.0078125f, var = ss*0.0078125f - m*m;
    float rstd = rsqrtf(var + 1e-5f);
    float4 gv = ((const float4*)lng)[q32], bv = ((const float4*)lnb)[q32];
    float4 sn;
    sn.x = (sv.x - m)*rstd*gv.x + bv.x;
    sn.y = (sv.y - m)*rstd*gv.y + bv.y;
    sn.z = (sv.z - m)*rstd*gv.z + bv.z;
    sn.w = (sv.w - m)*rstd*gv.w + bv.w;
    *(float4*)&sSn[t*4] = sn;
  }
  __syncthreads();
  {
    const float4* Wq4 = (const float4*)Wq;
    #pragma unroll
    for (int i = 0; i < 4; ++i){
      int e = i*32 + q32;
      float acc = 0.f;
      #pragma unroll
      for (int d4 = 0; d4 < 32; ++d4){
        float4 qs = *(const float4*)&sSn[k8*128 + d4*4];
        float4 wv = Wq4[e*32 + d4];
        acc = fmaf(qs.x,wv.x,acc); acc = fmaf(qs.y,wv.y,acc);
        acc = fmaf(qs.z,wv.z,acc); acc = fmaf(qs.w,wv.w,acc);
      }
      sQ[k8*128 + e] = acc * 0.08838834764831845f;
    }
  }
  __syncthreads();
  if (t < 128){
    int slot = t >> 4, g = t & 15;
    const float* src = &sQ[slot*128 + g*8];
    uint4 o;
    o.x = pk2(src[0], src[1]); o.y = pk2(src[2], src[3]);
    o.z = pk2(src[4], src[5]); o.w = pk2(src[6], src[7]);
    qg[(b*8 + slot)*16 + g] = o;
  }
}

// ---------------- kernel B: MFMA attention, double-buffered LDS, 1 barrier/tile ----------------
__global__ __launch_bounds__(256) void kB(const u16* __restrict__ kbuf,
   const u16* __restrict__ vbuf, const uint4* __restrict__ qg,
   float* __restrict__ part, float* __restrict__ attn_out, int write_attn,
   int cshift, int ntiles)
{
  const int t = threadIdx.x;
  const int b = blockIdx.x >> cshift, chunk = blockIdx.x & ((1 << cshift) - 1);
  const int w = t >> 6, l = t & 63;
  __shared__ __align__(16) u16 sVT[2][128*64];     // double-buffered (32 KB)
  __shared__ __align__(16) u16 sAttnB[2][16*64];   // double-buffered (4 KB)
  __shared__ float sRsP[32];

  uint4 qf[4];
  {
    int slot = l & 15;
    uint4 z = make_uint4(0,0,0,0);
    qf[0] = z; qf[1] = z; qf[2] = z; qf[3] = z;
    if (slot < 8){
      const uint4* qb = qg + ((size_t)b*8 + slot)*16 + (l >> 4);
      #pragma unroll
      for (int kt = 0; kt < 4; ++kt) qf[kt] = qb[kt*4];
    }
  }

  f32x4 accPV0 = (f32x4){0.f,0.f,0.f,0.f};
  f32x4 accPV1 = (f32x4){0.f,0.f,0.f,0.f};
  float rs = 0.f;
  const int myrow = w*16 + (l & 15);
  const size_t base = (size_t)b*4096 + (size_t)chunk*(ntiles*64);

  uint4 kf[4], vld[4];
  {
    const u16* kr = kbuf + (base + myrow)*128;
    #pragma unroll
    for (int kt = 0; kt < 4; ++kt) kf[kt] = *(const uint4*)(kr + (kt*4 + (l >> 4))*8);
    const uint4* vg = (const uint4*)(vbuf + base*128);
    #pragma unroll
    for (int p = 0; p < 4; ++p) vld[p] = vg[t + p*256];
  }

  #pragma unroll 2
  for (int tile = 0; tile < ntiles; ++tile){
    const int cur = tile & 1;
    const int n0 = tile*64;
    // QK^T from prefetched kf
    f32x4 dacc = (f32x4){0.f,0.f,0.f,0.f};
    #pragma unroll
    for (int kt = 0; kt < 4; ++kt)
      dacc = __builtin_amdgcn_mfma_f32_16x16x32_bf16(
          __builtin_bit_cast(bf16x8, kf[kt]),
          __builtin_bit_cast(bf16x8, qf[kt]), dacc, 0, 0, 0);
    // issue next tile's k AND v loads; softmax+staging below covers latency
    uint4 vldN[4];
    if (tile < ntiles - 1){
      const u16* kr = kbuf + (base + n0 + 64 + myrow)*128;
      #pragma unroll
      for (int kt = 0; kt < 4; ++kt) kf[kt] = *(const uint4*)(kr + (kt*4 + (l >> 4))*8);
      const uint4* vg = (const uint4*)(vbuf + (base + n0 + 64)*128);
      #pragma unroll
      for (int p = 0; p < 4; ++p) vldN[p] = vg[t + p*256];
    }
    // softmax over slots (8-lane xor groups)
    float at[4];
    #pragma unroll
    for (int r = 0; r < 4; ++r){
      float d = dacc[r];
      float mx = fmaxf(d, __shfl_xor(d, 1));
      mx = fmaxf(mx, __shfl_xor(mx, 2));
      mx = fmaxf(mx, __shfl_xor(mx, 4));
      float e = expf(d - mx);
      float ssum = e + __shfl_xor(e, 1);
      ssum += __shfl_xor(ssum, 2);
      ssum += __shfl_xor(ssum, 4);
      at[r] = e / ssum;
      rs += at[r];
    }
    {
      int slot = l & 15;
      int nb = w*16 + (l >> 4)*4;
      int g = (nb >> 3) ^ (slot & 7);
      *(u64*)((char*)sAttnB[cur] + slot*128 + (g << 4) + ((nb & 7) << 1)) =
          ((u64)pk2(at[2], at[3]) << 32) | (u64)pk2(at[0], at[1]);
    }
    // stage current v -> sVT[cur]
    #pragma unroll
    for (int p = 0; p < 4; ++p){
      int fl = t + p*256;
      int nl = fl >> 4, gb = fl & 15;
      u32 arr[4] = {vld[p].x, vld[p].y, vld[p].z, vld[p].w};
      #pragma unroll
      for (int hh = 0; hh < 4; ++hh){
        #pragma unroll
        for (int e2 = 0; e2 < 2; ++e2){
          int e = hh*2 + e2;
          int d = gb*8 + e;
          int g = (nl >> 3) ^ (d & 7) ^ (gb & 7);
          *(u16*)((char*)sVT[cur] + d*128 + (g << 4) + ((nl & 7) << 1)) =
              (u16)(e2 ? (arr[hh] >> 16) : (arr[hh] & 0xffffu));
        }
      }
    }
    if (write_attn && (l & 15) < 8){
      #pragma unroll
      for (int r = 0; r < 4; ++r)
        attn_out[(size_t)(b*8 + (l & 15))*4096 + chunk*(ntiles*64) + n0 + w*16 + (l >> 4)*4 + r] = at[r];
    }
    __syncthreads();   // the ONLY barrier per tile (dbuf: next stage hits other half)
    #pragma unroll
    for (int step = 0; step < 2; ++step){
      uint4 paf;
      {
        int slot = l & 15;
        int g = (step*4 + (l >> 4)) ^ (slot & 7);
        paf = *(const uint4*)((const char*)sAttnB[cur] + slot*128 + (g << 4));
      }
      #pragma unroll
      for (int ct = 0; ct < 2; ++ct){
        int d = w*32 + ct*16 + (l & 15);
        int g = (step*4 + (l >> 4)) ^ (d & 7) ^ ((d >> 3) & 7);
        uint4 pbf = *(const uint4*)((const char*)sVT[cur] + d*128 + (g << 4));
        if (ct == 0)
          accPV0 = __builtin_amdgcn_mfma_f32_16x16x32_bf16(
              __builtin_bit_cast(bf16x8, paf), __builtin_bit_cast(bf16x8, pbf), accPV0, 0,0,0);
        else
          accPV1 = __builtin_amdgcn_mfma_f32_16x16x32_bf16(
              __builtin_bit_cast(bf16x8, paf), __builtin_bit_cast(bf16x8, pbf), accPV1, 0,0,0);
      }
    }
    if (tile < ntiles - 1){
      #pragma unroll
      for (int p = 0; p < 4; ++p) vld[p] = vldN[p];
    }
  }

  __syncthreads();
  float* pb = part + (size_t)blockIdx.x*1040;
  if ((l >> 4) < 2){
    #pragma unroll
    for (int r = 0; r < 4; ++r){
      int slot = (l >> 4)*4 + r;
      pb[slot*128 + w*32 + (l & 15)] = accPV0[r];
      pb[slot*128 + w*32 + 16 + (l & 15)] = accPV1[r];
    }
  }
  rs += __shfl_xor(rs, 16);
  rs += __shfl_xor(rs, 32);
  if (l < 8) sRsP[w*8 + l] = rs;
  __syncthreads();
  if (t < 8) pb[1024 + t] = sRsP[t] + sRsP[8 + t] + sRsP[16 + t] + sRsP[24 + t];
}

// ---------------- kernel C: slot update + NEXT-ITERATION q (fused kQ) ----------------
__global__ __launch_bounds__(384) void kC(const float* __restrict__ part,
  float* __restrict__ slots, const float2* __restrict__ gruT,
  const float* __restrict__ bih, const float* __restrict__ bhh,
  const float* __restrict__ lng, const float* __restrict__ lnb,
  const float* __restrict__ w1T, const float* __restrict__ b1,
  const float* __restrict__ w2T, const float* __restrict__ b2,
  const float* __restrict__ lnslg, const float* __restrict__ lnslb,
  const float* __restrict__ Wq, uint4* __restrict__ qg,
  float* __restrict__ out_slots, int last, int nchunk)
{
  const int t = threadIdx.x;
  const int r = blockIdx.x, b = r >> 3, k = r & 7;
  __shared__ float sU[128], sS[128], sG1[384], sG2[384];
  __shared__ float sNew[128], sH[128], sH1[256];
  __shared__ float sP[4];

  if (t < 128){
    float rs = 1e-8f;
    for (int c = 0; c < nchunk; ++c) rs += part[(size_t)(b*nchunk + c)*1040 + 1024 + k];
    float u = 0.f;
    for (int c = 0; c < nchunk; ++c) u += part[(size_t)(b*nchunk + c)*1040 + k*128 + t];
    sU[t] = u / rs;
    sS[t] = slots[r*128 + t];
  }
  __syncthreads();

  {
    float acc1 = bih[t], acc2 = bhh[t];
    #pragma unroll 8
    for (int d = 0; d < 128; ++d){
      float2 w = gruT[d*384 + t];
      float ud = sU[d], sd = sS[d];
      acc1 = fmaf(ud, w.x, acc1);
      acc2 = fmaf(sd, w.y, acc2);
    }
    sG1[t] = acc1; sG2[t] = acc2;
  }
  __syncthreads();

  if (t < 128){
    float rr = 1.f/(1.f + expf(-(sG1[t] + sG2[t])));
    float zz = 1.f/(1.f + expf(-(sG1[128 + t] + sG2[128 + t])));
    float nn = tanhf(sG1[256 + t] + rr*sG2[256 + t]);
    sNew[t] = (1.f - zz)*nn + zz*sS[t];
  }
  __syncthreads();
  if (t < 128){
    float v = sNew[t];
    float s = v, ss = v*v;
    s  += __shfl_xor(s,1);  ss += __shfl_xor(ss,1);
    s  += __shfl_xor(s,2);  ss += __shfl_xor(ss,2);
    s  += __shfl_xor(s,4);  ss += __shfl_xor(ss,4);
    s  += __shfl_xor(s,8);  ss += __shfl_xor(ss,8);
    s  += __shfl_xor(s,16); ss += __shfl_xor(ss,16);
    s  += __shfl_xor(s,32); ss += __shfl_xor(ss,32);
    if ((t & 63) == 0){ sP[(t >> 6)*2] = s; sP[(t >> 6)*2 + 1] = ss; }
  }
  __syncthreads();
  if (t < 128){
    float s = sP[0] + sP[2], ss = sP[1] + sP[3];
    float m = s*0.0078125f, var = ss*0.0078125f - m*m;
    float rstd = rsqrtf(var + 1e-5f);
    sH[t] = (sNew[t] - m)*rstd*lng[t] + lnb[t];
  }
  __syncthreads();

  if (t < 256){
    float acc = b1[t];
    #pragma unroll 8
    for (int d = 0; d < 128; ++d)
      acc = fmaf(sH[d], w1T[d*256 + t], acc);
    sH1[t] = 0.5f*acc*(1.f + erff(acc*0.70710678118654752f));
  }
  __syncthreads();

  float res = 0.f;
  if (t < 128){
    float acc = b2[t];
    #pragma unroll 8
    for (int j = 0; j < 256; ++j)
      acc = fmaf(sH1[j], w2T[j*128 + t], acc);
    res = sNew[t] + acc;
    slots[r*128 + t] = res;
    if (last) out_slots[r*128 + t] = res;
  }
  if (last) return;

  // ---- fused next-iteration q: LN_sl(res) @ Wq^T * scale -> qg[r] ----
  __syncthreads();
  if (t < 128) sH[t] = res;
  __syncthreads();
  if (t < 128){
    float v = sH[t];
    float s = v, ss = v*v;
    s  += __shfl_xor(s,1);  ss += __shfl_xor(ss,1);
    s  += __shfl_xor(s,2);  ss += __shfl_xor(ss,2);
    s  += __shfl_xor(s,4);  ss += __shfl_xor(ss,4);
    s  += __shfl_xor(s,8);  ss += __shfl_xor(ss,8);
    s  += __shfl_xor(s,16); ss += __shfl_xor(ss,16);
    s  += __shfl_xor(s,32); ss += __shfl_xor(ss,32);
    if ((t & 63) == 0){ sP[(t >> 6)*2] = s; sP[(t >> 6)*2 + 1] = ss; }
  }
  __syncthreads();
  if (t < 128){
    float s = sP[0] + sP[2], ss = sP[1] + sP[3];
    float m = s*0.0078125f, var = ss*0.0078125f - m*m;
    float rstd = rsqrtf(var + 1e-5f);
    sU[t] = (sH[t] - m)*rstd*lnslg[t] + lnslb[t];
  }
  __syncthreads();
  if (t < 128){
    const float4* Wq4 = (const float4*)Wq;
    float acc = 0.f;
    #pragma unroll 8
    for (int d4 = 0; d4 < 32; ++d4){
      float4 wv = Wq4[t*32 + d4];
      float4 hv = *(const float4*)&sU[d4*4];
      acc = fmaf(wv.x,hv.x,acc); acc = fmaf(wv.y,hv.y,acc);
      acc = fmaf(wv.z,hv.z,acc); acc = fmaf(wv.w,hv.w,acc);
    }
    sG1[t] = acc * 0.08838834764831845f;
  }
  __syncthreads();
  if (t < 16){
    const float* src = &sG1[t*8];
    uint4 o;
    o.x = pk2(src[0], src[1]); o.y = pk2(src[2], src[3]);
    o.z = pk2(src[4], src[5]); o.w = pk2(src[6], src[7]);
    qg[(size_t)r*16 + t] = o;
  }
}

extern "C" void kernel_launch(void* const* d_in, const int* in_sizes, int n_in,
                              void* d_out, int out_size, void* d_ws, size_t ws_size,
                              hipStream_t stream)
{
  const float* inputs   = (const float*)d_in[0];
  const float* noise    = (const float*)d_in[1];
  const float* ln_in_g  = (const float*)d_in[2];
  const float* ln_in_b  = (const float*)d_in[3];
  const float* ln_sl_g  = (const float*)d_in[4];
  const float* ln_sl_b  = (const float*)d_in[5];
  const float* ln_mlp_g = (const float*)d_in[6];
  const float* ln_mlp_b = (const float*)d_in[7];
  const float* slots_mu = (const float*)d_in[8];
  const float* slots_ls = (const float*)d_in[9];
  const float* Wq  = (const float*)d_in[10];
  const float* Wk  = (const float*)d_in[11];
  const float* Wv  = (const float*)d_in[12];
  const float* Wih = (const float*)d_in[13];
  const float* Whh = (const float*)d_in[14];
  const float* bih = (const float*)d_in[15];
  const float* bhh = (const float*)d_in[16];
  const float* W1  = (const float*)d_in[17];
  const float* b1  = (const float*)d_in[18];
  const float* W2  = (const float*)d_in[19];
  const float* b2  = (const float*)d_in[20];
  float* out = (float*)d_out;

  char* ws = (char*)d_ws;
  u16*   kbuf  = (u16*)ws;                       // 67,108,864 B
  u16*   vbuf  = (u16*)(ws + 67108864);          // 67,108,864 B
  float* slots = (float*)(ws + 134217728);       // 262,144 B
  u16*   wg    = (u16*)(ws + 134479872);         // 65,536 B
  float* c1    = (float*)(ws + 134545408);       // 1,024 B
  float* c2    = (float*)(ws + 134546432);       // 1,024 B
  float* part  = (float*)(ws + 134547456);       // nchunk*64*1040*4 B

  int cshift, nchunk;
  {
    size_t need16 = 134547456ull + 16ull*64*1040*4 + 393216 + 131072 + 131072 + 131072;
    if (ws_size >= need16){ cshift = 4; nchunk = 16; }
    else                  { cshift = 3; nchunk = 8;  }
  }
  size_t partB = (size_t)nchunk*64*1040*4;
  float2* gruT = (float2*)(ws + 134547456 + partB);
  float*  w1T  = (float*)(ws + 134547456 + partB + 393216);
  float*  w2T  = (float*)(ws + 134547456 + partB + 393216 + 131072);
  uint4*  qg   = (uint4*)(ws + 134547456 + partB + 393216 + 262144);
  int ntiles = 64 / nchunk;

  kInitSlots<<<64, 256, 0, stream>>>(noise, slots_mu, slots_ls, slots);
  kInitW<<<1, 256, 0, stream>>>(Wk, Wv, ln_in_g, ln_in_b, wg, c1, c2);
  kInitT<<<448, 256, 0, stream>>>(Wih, Whh, W1, W2, gruT, w1T, w2T);
  kA<<<4096, 256, 0, stream>>>(inputs, wg, c1, c2, kbuf, vbuf);
  kQ<<<64, 256, 0, stream>>>(slots, Wq, ln_sl_g, ln_sl_b, qg);
  for (int it = 0; it < 3; ++it){
    kB<<<64*nchunk, 256, 0, stream>>>(kbuf, vbuf, qg, part, out + 65536,
                                      it == 2, cshift, ntiles);
    kC<<<512, 384, 0, stream>>>(part, slots, gruT, bih, bhh,
                                ln_mlp_g, ln_mlp_b, w1T, b1, w2T, b2,
                                ln_sl_g, ln_sl_b, Wq, qg, out, it == 2, nchunk);
  }
}

// Round 18
// 312.206 us; speedup vs baseline: 1.0649x; 1.0649x over previous
//
#include <hip/hip_runtime.h>
#include <hip/hip_bf16.h>
#include <math.h>

typedef unsigned int u32;
typedef unsigned long long u64;
typedef unsigned short u16;
typedef __bf16 bf16x8 __attribute__((ext_vector_type(8)));
typedef float f32x4 __attribute__((ext_vector_type(4)));

#define DEV __device__ __forceinline__

DEV u32 bfr(float f){ u32 u = __float_as_uint(f); return (u + 0x7fffu + ((u>>16)&1u)) >> 16; }
DEV u16 b1v(float a){ return __builtin_bit_cast(u16, (__bf16)a); }
DEV u32 pk2(float a, float b){
  return (u32)__builtin_bit_cast(u16, (__bf16)a) | ((u32)__builtin_bit_cast(u16, (__bf16)b) << 16);
}
DEV float red32(float v){
  v += __shfl_xor(v,1); v += __shfl_xor(v,2); v += __shfl_xor(v,4);
  v += __shfl_xor(v,8); v += __shfl_xor(v,16); return v;
}

// ---------------- init: slots = mu + exp(ls)*noise ----------------
__global__ void kInitSlots(const float* __restrict__ noise, const float* __restrict__ mu,
                           const float* __restrict__ ls, float* __restrict__ slots){
  int i4 = blockIdx.x*256 + threadIdx.x;
  int d4 = i4 & 31;
  float4 nv = ((const float4*)noise)[i4];
  float4 mv = ((const float4*)mu)[d4];
  float4 lv = ((const float4*)ls)[d4];
  float4 r;
  r.x = mv.x + expf(lv.x)*nv.x;
  r.y = mv.y + expf(lv.y)*nv.y;
  r.z = mv.z + expf(lv.z)*nv.z;
  r.w = mv.w + expf(lv.w)*nv.w;
  ((float4*)slots)[i4] = r;
}

// ---------------- init: Wg = [Wk;Wv]*g (bf16) with k-PERMUTED columns ----------------
__global__ void kInitW(const float* __restrict__ Wk, const float* __restrict__ Wv,
                       const float* __restrict__ g, const float* __restrict__ bb,
                       u16* __restrict__ wg, float* __restrict__ c1, float* __restrict__ c2){
  int e = threadIdx.x;
  const float4* src = (const float4*)((e < 128) ? (Wk + e*128) : (Wv + (e-128)*128));
  const float4* g4 = (const float4*)g;
  const float4* b4 = (const float4*)bb;
  float a1 = 0.f, a2 = 0.f;
  #pragma unroll
  for (int gr = 0; gr < 16; ++gr){
    int kt = gr >> 2, h = gr & 3;
    int iA = kt*8 + h, iB = kt*8 + 4 + h;
    float4 wa = src[iA], wb = src[iB];
    float4 ga = g4[iA], gb = g4[iB];
    float4 ba = b4[iA], bbv = b4[iB];
    a1 += wa.x*ga.x + wa.y*ga.y + wa.z*ga.z + wa.w*ga.w
        + wb.x*gb.x + wb.y*gb.y + wb.z*gb.z + wb.w*gb.w;
    a2 += wa.x*ba.x + wa.y*ba.y + wa.z*ba.z + wa.w*ba.w
        + wb.x*bbv.x + wb.y*bbv.y + wb.z*bbv.z + wb.w*bbv.w;
    uint4 o;
    o.x = pk2(wa.x*ga.x, wa.y*ga.y);
    o.y = pk2(wa.z*ga.z, wa.w*ga.w);
    o.z = pk2(wb.x*gb.x, wb.y*gb.y);
    o.w = pk2(wb.z*gb.z, wb.w*gb.w);
    *(uint4*)&wg[e*128 + gr*8] = o;
  }
  c1[e] = a1; c2[e] = a2;
}

// ---------------- init: transposed weight packs for kC ----------------
__global__ void kInitT(const float* __restrict__ Wih, const float* __restrict__ Whh,
                       const float* __restrict__ W1, const float* __restrict__ W2,
                       float2* __restrict__ gruT, float* __restrict__ w1T, float* __restrict__ w2T){
  int i = blockIdx.x*256 + threadIdx.x;
  if (i < 49152){
    int d = i / 384, g = i - d*384;
    gruT[i] = make_float2(Wih[g*128 + d], Whh[g*128 + d]);
  } else if (i < 81920){
    int j = i - 49152;
    int d = j >> 8, h = j & 255;
    w1T[j] = W1[h*128 + d];
  } else if (i < 114688){
    int q = i - 81920;
    int j = q >> 7, d = q & 127;
    w2T[q] = W2[d*256 + j];
  }
}

// ---------------- kernel A: fused-LN K/V projection via bf16 MFMA ----------------
// Round-14 structure (loads/stats/pack once per row) with the ct-loop split into
// TWO sequential 4-tile passes: per-pass acc[4] = 16 AGPR (was acc[8]=32).
// Target total regs <= 128 -> 128-reg quantum -> 4 waves/SIMD reg-wise; LDS
// 41KB -> 3 blocks/CU -> 12 waves/CU (1.5x round-14). No work duplication
// (round-17's col-split regressed because it doubled loads+stats).
#define CTPASS(P)                                                              \
  {                                                                            \
    f32x4 acc[4];                                                              \
    _Pragma("unroll")                                                          \
    for (int c_ = 0; c_ < 4; ++c_) acc[c_] = (f32x4){0.f,0.f,0.f,0.f};         \
    _Pragma("unroll")                                                          \
    for (int c4 = 0; c4 < 4; ++c4){                                            \
      int ct = P*4 + c4;                                                       \
      uint4 bf[4];                                                             \
      _Pragma("unroll")                                                        \
      for (int kt = 0; kt < 4; ++kt){                                          \
        int wr = ct*16 + (l & 15);                                             \
        int g = kt*4 + h;                                                      \
        bf[kt] = *(const uint4*)&sWg[wr*128 + ((g ^ (wr & 7)) << 3)];          \
      }                                                                        \
      _Pragma("unroll")                                                        \
      for (int kt = 0; kt < 4; ++kt)                                           \
        acc[c4] = __builtin_amdgcn_mfma_f32_16x16x32_bf16(                     \
            __builtin_bit_cast(bf16x8, af[kt]),                                \
            __builtin_bit_cast(bf16x8, bf[kt]), acc[c4], 0, 0, 0);             \
    }                                                                          \
    _Pragma("unroll")                                                          \
    for (int c4 = 0; c4 < 4; ++c4){                                            \
      int coll = c4*16 + (l & 15);                                             \
      float c1v = sC1[P*64 + coll], c2v = sC2[P*64 + coll];                    \
      _Pragma("unroll")                                                        \
      for (int r = 0; r < 4; ++r){                                             \
        int rl = h*4 + r;                                                      \
        float valf = rvp[r]*(acc[c4][r] - mvp[r]*c1v) + c2v;                   \
        int gran = (coll >> 3) ^ (rl & 7);                                     \
        sE[w*1024 + rl*64 + (gran << 3) + (coll & 7)] = b1v(valf);             \
      }                                                                        \
    }                                                                          \
    _Pragma("unroll")                                                          \
    for (int p = 0; p < 2; ++p){                                               \
      int fl = l + p*64;                                                       \
      int nl = fl >> 3, gb = fl & 7;                                           \
      uint4 v = *(const uint4*)&sE[w*1024 + nl*64 + ((gb ^ (nl & 7)) << 3)];   \
      dst4[(size_t)(r0 + nl)*16 + P*8 + gb] = v;                               \
    }                                                                          \
  }

__global__ __launch_bounds__(256, 2) void kA(const float* __restrict__ x,
    const u16* __restrict__ wg, const float* __restrict__ c1g, const float* __restrict__ c2g,
    u16* __restrict__ kbuf, u16* __restrict__ vbuf)
{
  __shared__ __align__(16) u16 sWg[128*128];     // 32 KB
  __shared__ __align__(16) u16 sE[4*16*64];      // 8 KB (4 waves x 2 KB)
  __shared__ float sC1[128], sC2[128];
  const int t = threadIdx.x, l = t & 63, w = t >> 6;   // w 0..3
  const int bid = blockIdx.x;
  const int half = (bid >> 3) & 1;                     // 0 = K cols, 1 = V cols
  const int q = bid >> 4;                              // 0..127
  const int rowgroup = (bid & 7)*32 + (q & 31);        // 0..255
  const int sub = q >> 5;                              // 0..3
  const int rowbase = rowgroup*1024 + sub*256;
  const int h = l >> 4;

  const uint4* wg4 = (const uint4*)wg;
  #pragma unroll
  for (int p = 0; p < 8; ++p){
    int G = t + p*256;
    int row = G >> 4, g = G & 15;
    uint4 v = wg4[(half*128 + row)*16 + g];
    *(uint4*)&sWg[row*128 + ((g ^ (row & 7)) << 3)] = v;
  }
  if (t < 128){ sC1[t] = c1g[half*128 + t]; sC2[t] = c2g[half*128 + t]; }
  __syncthreads();   // the ONLY barrier

  u16* dstbuf = half ? vbuf : kbuf;
  uint4* dst4 = (uint4*)dstbuf;
  const float4* x4 = (const float4*)x;

  #pragma unroll 1
  for (int it = 0; it < 4; ++it){
    const int r0 = rowbase + it*64 + w*16;
    const int myrow = r0 + (l & 15);
    float s1 = 0.f, s2 = 0.f;
    uint4 af[4];
    #pragma unroll
    for (int kt = 0; kt < 4; ++kt){
      float4 A = x4[(size_t)myrow*32 + kt*8 + h];        // 64B-contig per 4-lane grp
      float4 B = x4[(size_t)myrow*32 + kt*8 + 4 + h];
      s1 += A.x + A.y + A.z + A.w + B.x + B.y + B.z + B.w;
      s2 += A.x*A.x + A.y*A.y + A.z*A.z + A.w*A.w
          + B.x*B.x + B.y*B.y + B.z*B.z + B.w*B.w;
      af[kt].x = pk2(A.x, A.y);
      af[kt].y = pk2(A.z, A.w);
      af[kt].z = pk2(B.x, B.y);
      af[kt].w = pk2(B.z, B.w);
    }
    s1 += __shfl_xor(s1, 16); s2 += __shfl_xor(s2, 16);
    s1 += __shfl_xor(s1, 32); s2 += __shfl_xor(s2, 32);
    float m = s1 * 0.0078125f;
    float rstd = rsqrtf(s2 * 0.0078125f - m*m + 1e-5f);
    float mvp[4], rvp[4];
    #pragma unroll
    for (int r = 0; r < 4; ++r){
      int rl = h*4 + r;
      mvp[r] = __shfl(m, rl);
      rvp[r] = __shfl(rstd, rl);
    }
    CTPASS(0)
    CTPASS(1)
  }
}

// ---------------- kernel Q: iteration-0 q from initial slots ----------------
__global__ __launch_bounds__(256) void kQ(const float* __restrict__ slots,
    const float* __restrict__ Wq, const float* __restrict__ lng, const float* __restrict__ lnb,
    uint4* __restrict__ qg)
{
  const int b = blockIdx.x, t = threadIdx.x;
  const int k8 = t >> 5, q32 = t & 31;
  __shared__ __align__(16) float sSn[1024];
  __shared__ __align__(16) float sQ[1024];
  {
    float4 sv = ((const float4*)slots)[b*256 + t];
    float s  = sv.x + sv.y + sv.z + sv.w;
    float ss = sv.x*sv.x + sv.y*sv.y + sv.z*sv.z + sv.w*sv.w;
    s = red32(s); ss = red32(ss);
    float m = s*0.0078125f, var = ss*0.0078125f - m*m;
    float rstd = rsqrtf(var + 1e-5f);
    float4 gv = ((const float4*)lng)[q32], bv = ((const float4*)lnb)[q32];
    float4 sn;
    sn.x = (sv.x - m)*rstd*gv.x + bv.x;
    sn.y = (sv.y - m)*rstd*gv.y + bv.y;
    sn.z = (sv.z - m)*rstd*gv.z + bv.z;
    sn.w = (sv.w - m)*rstd*gv.w + bv.w;
    *(float4*)&sSn[t*4] = sn;
  }
  __syncthreads();
  {
    const float4* Wq4 = (const float4*)Wq;
    #pragma unroll
    for (int i = 0; i < 4; ++i){
      int e = i*32 + q32;
      float acc = 0.f;
      #pragma unroll
      for (int d4 = 0; d4 < 32; ++d4){
        float4 qs = *(const float4*)&sSn[k8*128 + d4*4];
        float4 wv = Wq4[e*32 + d4];
        acc = fmaf(qs.x,wv.x,acc); acc = fmaf(qs.y,wv.y,acc);
        acc = fmaf(qs.z,wv.z,acc); acc = fmaf(qs.w,wv.w,acc);
      }
      sQ[k8*128 + e] = acc * 0.08838834764831845f;
    }
  }
  __syncthreads();
  if (t < 128){
    int slot = t >> 4, g = t & 15;
    const float* src = &sQ[slot*128 + g*8];
    uint4 o;
    o.x = pk2(src[0], src[1]); o.y = pk2(src[2], src[3]);
    o.z = pk2(src[4], src[5]); o.w = pk2(src[6], src[7]);
    qg[(b*8 + slot)*16 + g] = o;
  }
}

// ---------------- kernel B: MFMA attention, double-buffered LDS, 1 barrier/tile ----------------
__global__ __launch_bounds__(256) void kB(const u16* __restrict__ kbuf,
   const u16* __restrict__ vbuf, const uint4* __restrict__ qg,
   float* __restrict__ part, float* __restrict__ attn_out, int write_attn,
   int cshift, int ntiles)
{
  const int t = threadIdx.x;
  const int b = blockIdx.x >> cshift, chunk = blockIdx.x & ((1 << cshift) - 1);
  const int w = t >> 6, l = t & 63;
  __shared__ __align__(16) u16 sVT[2][128*64];     // double-buffered (32 KB)
  __shared__ __align__(16) u16 sAttnB[2][16*64];   // double-buffered (4 KB)
  __shared__ float sRsP[32];

  uint4 qf[4];
  {
    int slot = l & 15;
    uint4 z = make_uint4(0,0,0,0);
    qf[0] = z; qf[1] = z; qf[2] = z; qf[3] = z;
    if (slot < 8){
      const uint4* qb = qg + ((size_t)b*8 + slot)*16 + (l >> 4);
      #pragma unroll
      for (int kt = 0; kt < 4; ++kt) qf[kt] = qb[kt*4];
    }
  }

  f32x4 accPV0 = (f32x4){0.f,0.f,0.f,0.f};
  f32x4 accPV1 = (f32x4){0.f,0.f,0.f,0.f};
  float rs = 0.f;
  const int myrow = w*16 + (l & 15);
  const size_t base = (size_t)b*4096 + (size_t)chunk*(ntiles*64);

  uint4 kf[4], vld[4];
  {
    const u16* kr = kbuf + (base + myrow)*128;
    #pragma unroll
    for (int kt = 0; kt < 4; ++kt) kf[kt] = *(const uint4*)(kr + (kt*4 + (l >> 4))*8);
    const uint4* vg = (const uint4*)(vbuf + base*128);
    #pragma unroll
    for (int p = 0; p < 4; ++p) vld[p] = vg[t + p*256];
  }

  #pragma unroll 2
  for (int tile = 0; tile < ntiles; ++tile){
    const int cur = tile & 1;
    const int n0 = tile*64;
    // QK^T from prefetched kf
    f32x4 dacc = (f32x4){0.f,0.f,0.f,0.f};
    #pragma unroll
    for (int kt = 0; kt < 4; ++kt)
      dacc = __builtin_amdgcn_mfma_f32_16x16x32_bf16(
          __builtin_bit_cast(bf16x8, kf[kt]),
          __builtin_bit_cast(bf16x8, qf[kt]), dacc, 0, 0, 0);
    // issue next tile's k AND v loads; softmax+staging below covers latency
    uint4 vldN[4];
    if (tile < ntiles - 1){
      const u16* kr = kbuf + (base + n0 + 64 + myrow)*128;
      #pragma unroll
      for (int kt = 0; kt < 4; ++kt) kf[kt] = *(const uint4*)(kr + (kt*4 + (l >> 4))*8);
      const uint4* vg = (const uint4*)(vbuf + (base + n0 + 64)*128);
      #pragma unroll
      for (int p = 0; p < 4; ++p) vldN[p] = vg[t + p*256];
    }
    // softmax over slots (8-lane xor groups)
    float at[4];
    #pragma unroll
    for (int r = 0; r < 4; ++r){
      float d = dacc[r];
      float mx = fmaxf(d, __shfl_xor(d, 1));
      mx = fmaxf(mx, __shfl_xor(mx, 2));
      mx = fmaxf(mx, __shfl_xor(mx, 4));
      float e = expf(d - mx);
      float ssum = e + __shfl_xor(e, 1);
      ssum += __shfl_xor(ssum, 2);
      ssum += __shfl_xor(ssum, 4);
      at[r] = e / ssum;
      rs += at[r];
    }
    {
      int slot = l & 15;
      int nb = w*16 + (l >> 4)*4;
      int g = (nb >> 3) ^ (slot & 7);
      *(u64*)((char*)sAttnB[cur] + slot*128 + (g << 4) + ((nb & 7) << 1)) =
          ((u64)pk2(at[2], at[3]) << 32) | (u64)pk2(at[0], at[1]);
    }
    // stage current v -> sVT[cur]
    #pragma unroll
    for (int p = 0; p < 4; ++p){
      int fl = t + p*256;
      int nl = fl >> 4, gb = fl & 15;
      u32 arr[4] = {vld[p].x, vld[p].y, vld[p].z, vld[p].w};
      #pragma unroll
      for (int hh = 0; hh < 4; ++hh){
        #pragma unroll
        for (int e2 = 0; e2 < 2; ++e2){
          int e = hh*2 + e2;
          int d = gb*8 + e;
          int g = (nl >> 3) ^ (d & 7) ^ (gb & 7);
          *(u16*)((char*)sVT[cur] + d*128 + (g << 4) + ((nl & 7) << 1)) =
              (u16)(e2 ? (arr[hh] >> 16) : (arr[hh] & 0xffffu));
        }
      }
    }
    if (write_attn && (l & 15) < 8){
      #pragma unroll
      for (int r = 0; r < 4; ++r)
        attn_out[(size_t)(b*8 + (l & 15))*4096 + chunk*(ntiles*64) + n0 + w*16 + (l >> 4)*4 + r] = at[r];
    }
    __syncthreads();   // the ONLY barrier per tile (dbuf: next stage hits other half)
    #pragma unroll
    for (int step = 0; step < 2; ++step){
      uint4 paf;
      {
        int slot = l & 15;
        int g = (step*4 + (l >> 4)) ^ (slot & 7);
        paf = *(const uint4*)((const char*)sAttnB[cur] + slot*128 + (g << 4));
      }
      #pragma unroll
      for (int ct = 0; ct < 2; ++ct){
        int d = w*32 + ct*16 + (l & 15);
        int g = (step*4 + (l >> 4)) ^ (d & 7) ^ ((d >> 3) & 7);
        uint4 pbf = *(const uint4*)((const char*)sVT[cur] + d*128 + (g << 4));
        if (ct == 0)
          accPV0 = __builtin_amdgcn_mfma_f32_16x16x32_bf16(
              __builtin_bit_cast(bf16x8, paf), __builtin_bit_cast(bf16x8, pbf), accPV0, 0,0,0);
        else
          accPV1 = __builtin_amdgcn_mfma_f32_16x16x32_bf16(
              __builtin_bit_cast(bf16x8, paf), __builtin_bit_cast(bf16x8, pbf), accPV1, 0,0,0);
      }
    }
    if (tile < ntiles - 1){
      #pragma unroll
      for (int p = 0; p < 4; ++p) vld[p] = vldN[p];
    }
  }

  __syncthreads();
  float* pb = part + (size_t)blockIdx.x*1040;
  if ((l >> 4) < 2){
    #pragma unroll
    for (int r = 0; r < 4; ++r){
      int slot = (l >> 4)*4 + r;
      pb[slot*128 + w*32 + (l & 15)] = accPV0[r];
      pb[slot*128 + w*32 + 16 + (l & 15)] = accPV1[r];
    }
  }
  rs += __shfl_xor(rs, 16);
  rs += __shfl_xor(rs, 32);
  if (l < 8) sRsP[w*8 + l] = rs;
  __syncthreads();
  if (t < 8) pb[1024 + t] = sRsP[t] + sRsP[8 + t] + sRsP[16 + t] + sRsP[24 + t];
}

// ---------------- kernel C: slot update + NEXT-ITERATION q (fused kQ) ----------------
__global__ __launch_bounds__(384) void kC(const float* __restrict__ part,
  float* __restrict__ slots, const float2* __restrict__ gruT,
  const float* __restrict__ bih, const float* __restrict__ bhh,
  const float* __restrict__ lng, const float* __restrict__ lnb,
  const float* __restrict__ w1T, const float* __restrict__ b1,
  const float* __restrict__ w2T, const float* __restrict__ b2,
  const float* __restrict__ lnslg, const float* __restrict__ lnslb,
  const float* __restrict__ Wq, uint4* __restrict__ qg,
  float* __restrict__ out_slots, int last, int nchunk)
{
  const int t = threadIdx.x;
  const int r = blockIdx.x, b = r >> 3, k = r & 7;
  __shared__ float sU[128], sS[128], sG1[384], sG2[384];
  __shared__ float sNew[128], sH[128], sH1[256];
  __shared__ float sP[4];

  if (t < 128){
    float rs = 1e-8f;
    for (int c = 0; c < nchunk; ++c) rs += part[(size_t)(b*nchunk + c)*1040 + 1024 + k];
    float u = 0.f;
    for (int c = 0; c < nchunk; ++c) u += part[(size_t)(b*nchunk + c)*1040 + k*128 + t];
    sU[t] = u / rs;
    sS[t] = slots[r*128 + t];
  }
  __syncthreads();

  {
    float acc1 = bih[t], acc2 = bhh[t];
    #pragma unroll 8
    for (int d = 0; d < 128; ++d){
      float2 w = gruT[d*384 + t];
      float ud = sU[d], sd = sS[d];
      acc1 = fmaf(ud, w.x, acc1);
      acc2 = fmaf(sd, w.y, acc2);
    }
    sG1[t] = acc1; sG2[t] = acc2;
  }
  __syncthreads();

  if (t < 128){
    float rr = 1.f/(1.f + expf(-(sG1[t] + sG2[t])));
    float zz = 1.f/(1.f + expf(-(sG1[128 + t] + sG2[128 + t])));
    float nn = tanhf(sG1[256 + t] + rr*sG2[256 + t]);
    sNew[t] = (1.f - zz)*nn + zz*sS[t];
  }
  __syncthreads();
  if (t < 128){
    float v = sNew[t];
    float s = v, ss = v*v;
    s  += __shfl_xor(s,1);  ss += __shfl_xor(ss,1);
    s  += __shfl_xor(s,2);  ss += __shfl_xor(ss,2);
    s  += __shfl_xor(s,4);  ss += __shfl_xor(ss,4);
    s  += __shfl_xor(s,8);  ss += __shfl_xor(ss,8);
    s  += __shfl_xor(s,16); ss += __shfl_xor(ss,16);
    s  += __shfl_xor(s,32); ss += __shfl_xor(ss,32);
    if ((t & 63) == 0){ sP[(t >> 6)*2] = s; sP[(t >> 6)*2 + 1] = ss; }
  }
  __syncthreads();
  if (t < 128){
    float s = sP[0] + sP[2], ss = sP[1] + sP[3];
    float m = s*0.0078125f, var = ss*0.0078125f - m*m;
    float rstd = rsqrtf(var + 1e-5f);
    sH[t] = (sNew[t] - m)*rstd*lng[t] + lnb[t];
  }
  __syncthreads();

  if (t < 256){
    float acc = b1[t];
    #pragma unroll 8
    for (int d = 0; d < 128; ++d)
      acc = fmaf(sH[d], w1T[d*256 + t], acc);
    sH1[t] = 0.5f*acc*(1.f + erff(acc*0.70710678118654752f));
  }
  __syncthreads();

  float res = 0.f;
  if (t < 128){
    float acc = b2[t];
    #pragma unroll 8
    for (int j = 0; j < 256; ++j)
      acc = fmaf(sH1[j], w2T[j*128 + t], acc);
    res = sNew[t] + acc;
    slots[r*128 + t] = res;
    if (last) out_slots[r*128 + t] = res;
  }
  if (last) return;

  // ---- fused next-iteration q: LN_sl(res) @ Wq^T * scale -> qg[r] ----
  __syncthreads();
  if (t < 128) sH[t] = res;
  __syncthreads();
  if (t < 128){
    float v = sH[t];
    float s = v, ss = v*v;
    s  += __shfl_xor(s,1);  ss += __shfl_xor(ss,1);
    s  += __shfl_xor(s,2);  ss += __shfl_xor(ss,2);
    s  += __shfl_xor(s,4);  ss += __shfl_xor(ss,4);
    s  += __shfl_xor(s,8);  ss += __shfl_xor(ss,8);
    s  += __shfl_xor(s,16); ss += __shfl_xor(ss,16);
    s  += __shfl_xor(s,32); ss += __shfl_xor(ss,32);
    if ((t & 63) == 0){ sP[(t >> 6)*2] = s; sP[(t >> 6)*2 + 1] = ss; }
  }
  __syncthreads();
  if (t < 128){
    float s = sP[0] + sP[2], ss = sP[1] + sP[3];
    float m = s*0.0078125f, var = ss*0.0078125f - m*m;
    float rstd = rsqrtf(var + 1e-5f);
    sU[t] = (sH[t] - m)*rstd*lnslg[t] + lnslb[t];
  }
  __syncthreads();
  if (t < 128){
    const float4* Wq4 = (const float4*)Wq;
    float acc = 0.f;
    #pragma unroll 8
    for (int d4 = 0; d4 < 32; ++d4){
      float4 wv = Wq4[t*32 + d4];
      float4 hv = *(const float4*)&sU[d4*4];
      acc = fmaf(wv.x,hv.x,acc); acc = fmaf(wv.y,hv.y,acc);
      acc = fmaf(wv.z,hv.z,acc); acc = fmaf(wv.w,hv.w,acc);
    }
    sG1[t] = acc * 0.08838834764831845f;
  }
  __syncthreads();
  if (t < 16){
    const float* src = &sG1[t*8];
    uint4 o;
    o.x = pk2(src[0], src[1]); o.y = pk2(src[2], src[3]);
    o.z = pk2(src[4], src[5]); o.w = pk2(src[6], src[7]);
    qg[(size_t)r*16 + t] = o;
  }
}

extern "C" void kernel_launch(void* const* d_in, const int* in_sizes, int n_in,
                              void* d_out, int out_size, void* d_ws, size_t ws_size,
                              hipStream_t stream)
{
  const float* inputs   = (const float*)d_in[0];
  const float* noise    = (const float*)d_in[1];
  const float* ln_in_g  = (const float*)d_in[2];
  const float* ln_in_b  = (const float*)d_in[3];
  const float* ln_sl_g  = (const float*)d_in[4];
  const float* ln_sl_b  = (const float*)d_in[5];
  const float* ln_mlp_g = (const float*)d_in[6];
  const float* ln_mlp_b = (const float*)d_in[7];
  const float* slots_mu = (const float*)d_in[8];
  const float* slots_ls = (const float*)d_in[9];
  const float* Wq  = (const float*)d_in[10];
  const float* Wk  = (const float*)d_in[11];
  const float* Wv  = (const float*)d_in[12];
  const float* Wih = (const float*)d_in[13];
  const float* Whh = (const float*)d_in[14];
  const float* bih = (const float*)d_in[15];
  const float* bhh = (const float*)d_in[16];
  const float* W1  = (const float*)d_in[17];
  const float* b1  = (const float*)d_in[18];
  const float* W2  = (const float*)d_in[19];
  const float* b2  = (const float*)d_in[20];
  float* out = (float*)d_out;

  char* ws = (char*)d_ws;
  u16*   kbuf  = (u16*)ws;                       // 67,108,864 B
  u16*   vbuf  = (u16*)(ws + 67108864);          // 67,108,864 B
  float* slots = (float*)(ws + 134217728);       // 262,144 B
  u16*   wg    = (u16*)(ws + 134479872);         // 65,536 B
  float* c1    = (float*)(ws + 134545408);       // 1,024 B
  float* c2    = (float*)(ws + 134546432);       // 1,024 B
  float* part  = (float*)(ws + 134547456);       // nchunk*64*1040*4 B

  int cshift, nchunk;
  {
    size_t need16 = 134547456ull + 16ull*64*1040*4 + 393216 + 131072 + 131072 + 131072;
    if (ws_size >= need16){ cshift = 4; nchunk = 16; }
    else                  { cshift = 3; nchunk = 8;  }
  }
  size_t partB = (size_t)nchunk*64*1040*4;
  float2* gruT = (float2*)(ws + 134547456 + partB);
  float*  w1T  = (float*)(ws + 134547456 + partB + 393216);
  float*  w2T  = (float*)(ws + 134547456 + partB + 393216 + 131072);
  uint4*  qg   = (uint4*)(ws + 134547456 + partB + 393216 + 262144);
  int ntiles = 64 / nchunk;

  kInitSlots<<<64, 256, 0, stream>>>(noise, slots_mu, slots_ls, slots);
  kInitW<<<1, 256, 0, stream>>>(Wk, Wv, ln_in_g, ln_in_b, wg, c1, c2);
  kInitT<<<448, 256, 0, stream>>>(Wih, Whh, W1, W2, gruT, w1T, w2T);
  kA<<<2048, 256, 0, stream>>>(inputs, wg, c1, c2, kbuf, vbuf);
  kQ<<<64, 256, 0, stream>>>(slots, Wq, ln_sl_g, ln_sl_b, qg);
  for (int it = 0; it < 3; ++it){
    kB<<<64*nchunk, 256, 0, stream>>>(kbuf, vbuf, qg, part, out + 65536,
                                      it == 2, cshift, ntiles);
    kC<<<512, 384, 0, stream>>>(part, slots, gruT, bih, bhh,
                                ln_mlp_g, ln_mlp_b, w1T, b1, w2T, b2,
                                ln_sl_g, ln_sl_b, Wq, qg, out, it == 2, nchunk);
  }
}